// Round 1
// baseline (814.797 us; speedup 1.0000x reference)
//
#include <hip/hip_runtime.h>

#define N_ 512
#define NPOS (N_*N_)   // 262144
#define CD 128         // C == CZ == 128

typedef unsigned short ushort_t;
typedef unsigned int   uint_t;
typedef __bf16 bf16_t;
typedef bf16_t  bf16x8 __attribute__((ext_vector_type(8)));
typedef float   f32x4  __attribute__((ext_vector_type(4)));
typedef unsigned short u16x4 __attribute__((ext_vector_type(4)));
typedef uint_t  u32x4 __attribute__((ext_vector_type(4)));

__device__ __forceinline__ float bf2f(ushort_t h) {
  union { uint_t u; float f; } v; v.u = ((uint_t)h) << 16; return v.f;
}
__device__ __forceinline__ ushort_t f2bf(float f) {
  union { float f; uint_t u; } v; v.f = f;
  uint_t u = v.u;
  return (ushort_t)((u + 0x7FFFu + ((u >> 16) & 1u)) >> 16);
}
__device__ __forceinline__ float sigm(float x) { return 1.0f / (1.0f + __expf(-x)); }

// ---------------- weight transposes (f32 -> bf16): wT[m][c][k] = W_m[k][c] ----------------
__global__ void k_tw(const float* s0, const float* s1, const float* s2,
                     const float* s3, const float* s4, const float* s5,
                     ushort_t* dst) {
  const float* s;
  switch (blockIdx.x) {
    case 0: s = s0; break; case 1: s = s1; break; case 2: s = s2; break;
    case 3: s = s3; break; case 4: s = s4; break; default: s = s5; break;
  }
  ushort_t* d = dst + blockIdx.x * CD * CD;
  for (int idx = threadIdx.x; idx < CD * CD; idx += 256) {
    int c = idx >> 7, k = idx & 127;
    d[idx] = f2bf(s[k * CD + c]);
  }
}

// ---------------- LN1 (f32 in, bf16 out): one wave per row of 128 ----------------
__global__ void k_ln1(const float* __restrict__ x, const float* __restrict__ gma,
                      const float* __restrict__ bta, ushort_t* __restrict__ z) {
  int row  = blockIdx.x * 4 + (threadIdx.x >> 6);
  int lane = threadIdx.x & 63;
  float2 pv = ((const float2*)(x + (size_t)row * CD))[lane];
  float x0 = pv.x, x1 = pv.y;
  float s = x0 + x1, q = x0 * x0 + x1 * x1;
  #pragma unroll
  for (int o = 32; o > 0; o >>= 1) { s += __shfl_xor(s, o, 64); q += __shfl_xor(q, o, 64); }
  float mu = s * (1.0f / 128.0f);
  float rs = rsqrtf(q * (1.0f / 128.0f) - mu * mu + 1e-5f);
  float2 gv = ((const float2*)gma)[lane];
  float2 bv = ((const float2*)bta)[lane];
  float z0 = (x0 - mu) * rs * gv.x + bv.x;
  float z1 = (x1 - mu) * rs * gv.y + bv.y;
  ((uint_t*)(z + (size_t)row * CD))[lane] = (uint_t)f2bf(z0) | ((uint_t)f2bf(z1) << 16);
}

// ---------------- fused projections: a, b (gated, channel-major bf16) and g (f32) ----------------
// One block per 128-pos tile. z staged ONCE (XOR-swizzled). aT/bT stores go through an
// LDS transpose buffer so global writes are contiguous full-line row segments.
__global__ void k_proj(const ushort_t* __restrict__ z, const ushort_t* __restrict__ wT,
                       ushort_t* __restrict__ aT, ushort_t* __restrict__ bT,
                       float* __restrict__ g) {
  __shared__ ushort_t zl[128 * 128];   // 32KB, XOR-swizzled: 16B-unit (row,c16) at row*16 + (c16^(row&7))
  __shared__ ushort_t tb[128][80];     // 20KB transpose buffer: 128 couts x 64 pos (+pad, 160B row = 16B-mult)
  const int tid = threadIdx.x;
  const int lane = tid & 63, wid = tid >> 6;
  const int qd = lane >> 4, l15 = lane & 15;
  const int pos0 = blockIdx.x * 128;
  const int wm = wid & 1, wn = wid >> 1;   // wm: pos-dim half, wn: cout-dim half

  { // stage z tile once, swizzled (write side of the XOR involution)
    const u32x4* src = (const u32x4*)(z + (size_t)pos0 * CD);
    u32x4* dst = (u32x4*)zl;
    #pragma unroll
    for (int i = 0; i < 8; ++i) {
      int u = tid + i * 256;                       // 16B-chunk index, 0..2047
      int row = u >> 4;
      dst[(u & ~15) | ((u & 15) ^ (row & 7))] = src[u];
    }
  }
  __syncthreads();

  // swizzled read: kq = 16B-unit column (kk*4+qd)
  auto zread = [&](int row, int kq) -> bf16x8 {
    return ((const bf16x8*)zl)[(row << 4) | (kq ^ (row & 7))];
  };

  // ---- modes a and b: gated GEMMs, channel-major output via LDS transpose ----
  #pragma unroll 1
  for (int ab = 0; ab < 2; ++ab) {
    const ushort_t* Wg = wT + (ab ? 2 : 0) * CD * CD;   // [cout][k]
    const ushort_t* Wv = wT + (ab ? 3 : 1) * CD * CD;
    f32x4 accg[4][4] = {}; f32x4 accv[4][4] = {};
    for (int kk = 0; kk < 4; ++kk) {
      bf16x8 af[4];
      #pragma unroll
      for (int i = 0; i < 4; ++i)
        af[i] = zread(wm * 64 + i * 16 + l15, kk * 4 + qd);
      #pragma unroll
      for (int j = 0; j < 4; ++j) {
        int crow = (wn * 64 + j * 16 + l15) * CD + kk * 32 + qd * 8;
        bf16x8 bg = *(const bf16x8*)(Wg + crow);
        bf16x8 bv = *(const bf16x8*)(Wv + crow);
        #pragma unroll
        for (int i = 0; i < 4; ++i) {
          accg[i][j] = __builtin_amdgcn_mfma_f32_16x16x32_bf16(af[i], bg, accg[i][j], 0, 0, 0);
          accv[i][j] = __builtin_amdgcn_mfma_f32_16x16x32_bf16(af[i], bv, accv[i][j], 0, 0, 0);
        }
      }
    }
    ushort_t* dst = ab ? bT : aT;   // [cout][pos]
    #pragma unroll 1
    for (int ph = 0; ph < 2; ++ph) {           // pos-half ph: waves with wm==ph own it
      __syncthreads();                          // tb free (previous consumers done)
      if (wm == ph) {
        #pragma unroll
        for (int i = 0; i < 4; ++i) {
          #pragma unroll
          for (int j = 0; j < 4; ++j) {
            int cout = wn * 64 + j * 16 + l15;
            u16x4 pk;
            #pragma unroll
            for (int r = 0; r < 4; ++r) pk[r] = f2bf(sigm(accg[i][j][r]) * accv[i][j][r]);
            *(u16x4*)&tb[cout][i * 16 + qd * 4] = pk;
          }
        }
      }
      __syncthreads();
      // cooperative store: 128 rows x 128B contiguous segments -> full-line writes
      #pragma unroll
      for (int it = 0; it < 4; ++it) {
        int idx = tid + it * 256;               // 16B chunks, 0..1023
        int row = idx >> 3, c16 = idx & 7;
        u32x4 v = *(const u32x4*)&tb[row][c16 * 8];
        *(u32x4*)&dst[(size_t)row * NPOS + pos0 + ph * 64 + c16 * 8] = v;
      }
    }
  }

  // ---- mode g: g = sigmoid(z @ wgate), f32 [pos][cz] ----
  {
    const ushort_t* Wg2 = wT + 4 * CD * CD;              // wgateT [cz][k]
    f32x4 acc[4][4] = {};
    for (int kk = 0; kk < 4; ++kk) {
      bf16x8 af[4];
      #pragma unroll
      for (int i = 0; i < 4; ++i)
        af[i] = *(const bf16x8*)(Wg2 + (wm * 64 + i * 16 + l15) * CD + kk * 32 + qd * 8);
      #pragma unroll
      for (int j = 0; j < 4; ++j) {
        bf16x8 bz = zread(wn * 64 + j * 16 + l15, kk * 4 + qd);
        #pragma unroll
        for (int i = 0; i < 4; ++i)
          acc[i][j] = __builtin_amdgcn_mfma_f32_16x16x32_bf16(af[i], bz, acc[i][j], 0, 0, 0);
      }
    }
    // D[cz][pos]: lane's 4 rows = 4 consecutive cz at one pos -> float4 store into g[pos][cz]
    #pragma unroll
    for (int i = 0; i < 4; ++i) {
      int cz = wm * 64 + i * 16 + qd * 4;
      #pragma unroll
      for (int j = 0; j < 4; ++j) {
        int pos = pos0 + wn * 64 + j * 16 + l15;
        float4 pk;
        pk.x = sigm(acc[i][j][0]); pk.y = sigm(acc[i][j][1]);
        pk.z = sigm(acc[i][j][2]); pk.w = sigm(acc[i][j][3]);
        *(float4*)&g[(size_t)pos * CD + cz] = pk;
      }
    }
  }
}

// ---------------- triangle einsum: per channel c, U_c = A_c · B_c^T (bf16) ----------------
__global__ void k_tri(const ushort_t* __restrict__ aT, const ushort_t* __restrict__ bT,
                      ushort_t* __restrict__ uT) {
  __shared__ ushort_t lA[128][32];  // 8KB
  __shared__ ushort_t lB[128][32];
  const int tid = threadIdx.x;
  const int lane = tid & 63, wid = tid >> 6;
  const int qd = lane >> 4, l15 = lane & 15;
  const int wm = wid & 1, wn = wid >> 1;
  const int c  = blockIdx.z;
  const int m0 = blockIdx.y * 128, n0 = blockIdx.x * 128;
  const ushort_t* A = aT + (size_t)c * NPOS;  // [512][512]
  const ushort_t* B = bT + (size_t)c * NPOS;
  const int sr = tid >> 2, sc = (tid & 3) * 8;   // staging row 0..63, col (ushorts)
  f32x4 acc[4][4] = {};
  for (int kk = 0; kk < N_; kk += 32) {
    __syncthreads();
    *(u32x4*)&lA[sr     ][sc] = *(const u32x4*)&A[(size_t)(m0 + sr)      * N_ + kk + sc];
    *(u32x4*)&lA[sr + 64][sc] = *(const u32x4*)&A[(size_t)(m0 + 64 + sr) * N_ + kk + sc];
    *(u32x4*)&lB[sr     ][sc] = *(const u32x4*)&B[(size_t)(n0 + sr)      * N_ + kk + sc];
    *(u32x4*)&lB[sr + 64][sc] = *(const u32x4*)&B[(size_t)(n0 + 64 + sr) * N_ + kk + sc];
    __syncthreads();
    bf16x8 af[4], bfr[4];
    #pragma unroll
    for (int t = 0; t < 4; ++t) af[t]  = *(const bf16x8*)&lA[wm * 64 + t * 16 + l15][qd * 8];
    #pragma unroll
    for (int t = 0; t < 4; ++t) bfr[t] = *(const bf16x8*)&lB[wn * 64 + t * 16 + l15][qd * 8];
    #pragma unroll
    for (int i = 0; i < 4; ++i)
      #pragma unroll
      for (int j = 0; j < 4; ++j)
        acc[i][j] = __builtin_amdgcn_mfma_f32_16x16x32_bf16(af[i], bfr[j], acc[i][j], 0, 0, 0);
  }
  ushort_t* U = uT + (size_t)c * NPOS;
  #pragma unroll
  for (int i = 0; i < 4; ++i) {
    int mr = m0 + wm * 64 + i * 16 + qd * 4;
    #pragma unroll
    for (int j = 0; j < 4; ++j) {
      int nc = n0 + wn * 64 + j * 16 + l15;
      #pragma unroll
      for (int r2 = 0; r2 < 4; ++r2)
        U[(size_t)(mr + r2) * N_ + nc] = f2bf(acc[i][j][r2]);
    }
  }
}

// ---------------- LN2 + @w_out + gate (f32 gate in d_out, overwritten in place) ----------------
__global__ void k_out(const ushort_t* __restrict__ uT, const ushort_t* __restrict__ wT,
                      const float* __restrict__ g2, const float* __restrict__ b2,
                      float* __restrict__ gout) {
  __shared__ ushort_t nu[128][136];   // [pos][c] padded, 34.8KB (raw then normalized)
  __shared__ float ps[2][128], pq[2][128];
  __shared__ float mu[128], rsd[128], gam[128], bet[128];
  const int tid = threadIdx.x;
  const int lane = tid & 63, wid = tid >> 6;
  const int qd = lane >> 4, l15 = lane & 15;
  const int pos0 = blockIdx.x * 128;
  const ushort_t* WoT = wT + 5 * CD * CD;   // w_outT [cz][c]

  if (tid < 128) { gam[tid] = g2[tid]; bet[tid] = b2[tid]; }

  { // pass 1: load raw U tile (transposed into nu[pos][c]) + LN2 stats
    int p = tid & 127, h = tid >> 7;
    float s = 0.f, sq = 0.f;
    for (int cc = h * 64; cc < h * 64 + 64; ++cc) {
      ushort_t raw = uT[(size_t)cc * NPOS + pos0 + p];
      nu[p][cc] = raw;
      float v = bf2f(raw); s += v; sq += v * v;
    }
    ps[h][p] = s; pq[h][p] = sq;
  }
  __syncthreads();
  if (tid < 128) {
    float s = ps[0][tid] + ps[1][tid];
    float m = s * (1.0f / 128.0f);
    float v = (pq[0][tid] + pq[1][tid]) * (1.0f / 128.0f) - m * m;
    mu[tid] = m; rsd[tid] = rsqrtf(v + 1e-5f);
  }
  __syncthreads();
  { // pass 2: normalize in place
    int p = tid & 127, h = tid >> 7;
    float m = mu[p], rs = rsd[p];
    for (int cc = h * 64; cc < h * 64 + 64; ++cc)
      nu[p][cc] = f2bf((bf2f(nu[p][cc]) - m) * rs * gam[cc] + bet[cc]);
  }
  __syncthreads();

  // GEMM: D[cz][pos] = WoT[cz][c] · nu[pos][c]^T
  const int wm = wid & 1, wn = wid >> 1;
  f32x4 acc[4][4] = {};
  for (int kk = 0; kk < 4; ++kk) {
    bf16x8 af[4];
    #pragma unroll
    for (int i = 0; i < 4; ++i)
      af[i] = *(const bf16x8*)(WoT + (wm * 64 + i * 16 + l15) * CD + kk * 32 + qd * 8);
    #pragma unroll
    for (int j = 0; j < 4; ++j) {
      bf16x8 bn = *(const bf16x8*)&nu[wn * 64 + j * 16 + l15][kk * 32 + qd * 8];
      #pragma unroll
      for (int i = 0; i < 4; ++i)
        acc[i][j] = __builtin_amdgcn_mfma_f32_16x16x32_bf16(af[i], bn, acc[i][j], 0, 0, 0);
    }
  }
  #pragma unroll
  for (int i = 0; i < 4; ++i) {
    int cz = wm * 64 + i * 16 + qd * 4;
    #pragma unroll
    for (int j = 0; j < 4; ++j) {
      int pos = pos0 + wn * 64 + j * 16 + l15;
      float4 gv = *(const float4*)&gout[(size_t)pos * CD + cz];   // read gate first
      float4 pk;
      pk.x = gv.x * acc[i][j][0]; pk.y = gv.y * acc[i][j][1];
      pk.z = gv.z * acc[i][j][2]; pk.w = gv.w * acc[i][j][3];
      *(float4*)&gout[(size_t)pos * CD + cz] = pk;                // overwrite with output
    }
  }
}

extern "C" void kernel_launch(void* const* d_in, const int* in_sizes, int n_in,
                              void* d_out, int out_size, void* d_ws, size_t ws_size,
                              hipStream_t stream) {
  const float* pair = (const float*)d_in[0];
  const float* g1   = (const float*)d_in[1];
  const float* b1   = (const float*)d_in[2];
  const float* wga  = (const float*)d_in[3];
  const float* wgb  = (const float*)d_in[4];
  const float* wa   = (const float*)d_in[5];
  const float* wb   = (const float*)d_in[6];
  const float* g2   = (const float*)d_in[7];
  const float* b2   = (const float*)d_in[8];
  const float* wout = (const float*)d_in[9];
  const float* wg   = (const float*)d_in[10];

  char* ws = (char*)d_ws;
  ushort_t* z  = (ushort_t*)(ws);                 // 64MiB bf16; reused as uT after k_proj
  ushort_t* aT = (ushort_t*)(ws + 67108864);      // 64MiB bf16 [c][pos]
  ushort_t* bT = (ushort_t*)(ws + 134217728);     // 64MiB bf16 [c][pos]
  ushort_t* wT = (ushort_t*)(ws + 201326592);     // 6 * 32KB transposed bf16 weights
  ushort_t* uT = z;
  float*    gb = (float*)d_out;                   // f32 gate staged in d_out, then final output

  k_tw  <<<6, 256, 0, stream>>>(wga, wa, wgb, wb, wg, wout, wT);
  k_ln1 <<<NPOS / 4, 256, 0, stream>>>(pair, g1, b1, z);
  k_proj<<<2048, 256, 0, stream>>>(z, wT, aT, bT, gb);
  k_tri <<<dim3(4, 4, 128), 256, 0, stream>>>(aT, bT, uT);
  k_out <<<2048, 256, 0, stream>>>(uT, wT, g2, b2, gb);
}

// Round 2
// 535.476 us; speedup vs baseline: 1.5216x; 1.5216x over previous
//
#include <hip/hip_runtime.h>

#define N_ 512
#define NPOS (N_*N_)   // 262144
#define CD 128         // C == CZ == 128

typedef unsigned short ushort_t;
typedef unsigned int   uint_t;
typedef __bf16 bf16_t;
typedef bf16_t  bf16x8 __attribute__((ext_vector_type(8)));
typedef float   f32x4  __attribute__((ext_vector_type(4)));
typedef unsigned short u16x4 __attribute__((ext_vector_type(4)));
typedef uint_t  u32x4 __attribute__((ext_vector_type(4)));

__device__ __forceinline__ float bf2f(ushort_t h) {
  union { uint_t u; float f; } v; v.u = ((uint_t)h) << 16; return v.f;
}
__device__ __forceinline__ ushort_t f2bf(float f) {
  union { float f; uint_t u; } v; v.f = f;
  uint_t u = v.u;
  return (ushort_t)((u + 0x7FFFu + ((u >> 16) & 1u)) >> 16);
}
__device__ __forceinline__ float sigm(float x) { return 1.0f / (1.0f + __expf(-x)); }

// ---------------- weight transposes (f32 -> bf16): wT[m][c][k] = W_m[k][c] ----------------
__global__ void k_tw(const float* s0, const float* s1, const float* s2,
                     const float* s3, const float* s4, const float* s5,
                     ushort_t* dst) {
  const float* s;
  switch (blockIdx.x) {
    case 0: s = s0; break; case 1: s = s1; break; case 2: s = s2; break;
    case 3: s = s3; break; case 4: s = s4; break; default: s = s5; break;
  }
  ushort_t* d = dst + blockIdx.x * CD * CD;
  for (int idx = threadIdx.x; idx < CD * CD; idx += 256) {
    int c = idx >> 7, k = idx & 127;
    d[idx] = f2bf(s[k * CD + c]);
  }
}

// ---------------- LN1 (f32 in, bf16 out): one wave per row of 128 ----------------
__global__ void k_ln1(const float* __restrict__ x, const float* __restrict__ gma,
                      const float* __restrict__ bta, ushort_t* __restrict__ z) {
  int row  = blockIdx.x * 4 + (threadIdx.x >> 6);
  int lane = threadIdx.x & 63;
  float2 pv = ((const float2*)(x + (size_t)row * CD))[lane];
  float x0 = pv.x, x1 = pv.y;
  float s = x0 + x1, q = x0 * x0 + x1 * x1;
  #pragma unroll
  for (int o = 32; o > 0; o >>= 1) { s += __shfl_xor(s, o, 64); q += __shfl_xor(q, o, 64); }
  float mu = s * (1.0f / 128.0f);
  float rs = rsqrtf(q * (1.0f / 128.0f) - mu * mu + 1e-5f);
  float2 gv = ((const float2*)gma)[lane];
  float2 bv = ((const float2*)bta)[lane];
  float z0 = (x0 - mu) * rs * gv.x + bv.x;
  float z1 = (x1 - mu) * rs * gv.y + bv.y;
  ((uint_t*)(z + (size_t)row * CD))[lane] = (uint_t)f2bf(z0) | ((uint_t)f2bf(z1) << 16);
}

// ---------------- projections: weights persistent in registers, z pipelined ----------------
// 256 blocks x 4 waves. Wave w owns couts [32w,32w+32) of ALL 5 weight matrices (160 VGPR).
// 8 pos-tiles per block: z reg-prefetched one tile ahead -> swizzled LDS -> pure ds_read+MFMA.
// a/b outputs via padded LDS transpose buffer -> full-line stores. g stored f32 direct.
__global__ __launch_bounds__(256, 1)
void k_proj(const ushort_t* __restrict__ z, const ushort_t* __restrict__ wT,
            ushort_t* __restrict__ aT, ushort_t* __restrict__ bT,
            float* __restrict__ g) {
  __shared__ ushort_t zl[128 * 128];   // 32KB, XOR-swizzled 16B units
  __shared__ ushort_t tb[128][136];    // 34KB transpose buffer, padded (272B rows, 16B-aligned)
  const int tid = threadIdx.x;
  const int lane = tid & 63, w = tid >> 6;
  const int qd = lane >> 4, l15 = lane & 15;

  // ---- persistent weight fragments: wf[m][i][kk] row = 32w+i*16+l15, col = kk*32+qd*8 ----
  bf16x8 wf[5][2][4];
  #pragma unroll
  for (int m = 0; m < 5; ++m)
    #pragma unroll
    for (int i = 0; i < 2; ++i)
      #pragma unroll
      for (int kk = 0; kk < 4; ++kk)
        wf[m][i][kk] = *(const bf16x8*)(wT + m * CD * CD + (w * 32 + i * 16 + l15) * CD + kk * 32 + qd * 8);

  const int TILES = 8;
  const int base = blockIdx.x * TILES;

  u32x4 st[8];
  { // prologue: prefetch tile 0 into registers
    const u32x4* src = (const u32x4*)(z + (size_t)base * 128 * CD);
    #pragma unroll
    for (int i = 0; i < 8; ++i) st[i] = src[tid + i * 256];
  }

  for (int t = 0; t < TILES; ++t) {
    const int pos0 = (base + t) * 128;
    __syncthreads();                       // prev tile's zl readers done
    { // staged regs -> swizzled zl
      u32x4* dst = (u32x4*)zl;
      #pragma unroll
      for (int i = 0; i < 8; ++i) {
        int u = tid + i * 256, row = u >> 4;
        dst[(u & ~15) | ((u & 15) ^ (row & 7))] = st[i];
      }
    }
    __syncthreads();                       // zl ready for all waves
    if (t + 1 < TILES) {                   // prefetch next tile (hidden under compute)
      const u32x4* src = (const u32x4*)(z + (size_t)(base + t + 1) * 128 * CD);
      #pragma unroll
      for (int i = 0; i < 8; ++i) st[i] = src[tid + i * 256];
    }

    // ---- modes a and b: gated dual GEMM, weights from registers ----
    #pragma unroll
    for (int ab = 0; ab < 2; ++ab) {
      f32x4 ag[2][8] = {}; f32x4 av[2][8] = {};
      #pragma unroll
      for (int kk = 0; kk < 4; ++kk) {
        bf16x8 zf[8];
        #pragma unroll
        for (int j = 0; j < 8; ++j) {
          int row = j * 16 + l15, kq = kk * 4 + qd;
          zf[j] = ((const bf16x8*)zl)[(row << 4) | (kq ^ (row & 7))];
        }
        #pragma unroll
        for (int j = 0; j < 8; ++j)
          #pragma unroll
          for (int i = 0; i < 2; ++i) {
            ag[i][j] = __builtin_amdgcn_mfma_f32_16x16x32_bf16(wf[ab * 2][i][kk],     zf[j], ag[i][j], 0, 0, 0);
            av[i][j] = __builtin_amdgcn_mfma_f32_16x16x32_bf16(wf[ab * 2 + 1][i][kk], zf[j], av[i][j], 0, 0, 0);
          }
      }
      // epilogue: gate, transpose via tb, full-line stores
      #pragma unroll
      for (int i = 0; i < 2; ++i)
        #pragma unroll
        for (int j = 0; j < 8; ++j)
          #pragma unroll
          for (int r = 0; r < 4; ++r)
            tb[w * 32 + i * 16 + qd * 4 + r][j * 16 + l15] = f2bf(sigm(ag[i][j][r]) * av[i][j][r]);
      __syncthreads();                     // tb complete
      {
        ushort_t* dst = ab ? bT : aT;      // [cout][pos], 256B contiguous per row
        #pragma unroll
        for (int it = 0; it < 8; ++it) {
          int idx = tid + it * 256;        // 2048 x 16B chunks
          int row = idx >> 4, c16 = idx & 15;
          u32x4 v = *(const u32x4*)&tb[row][c16 * 8];
          *(u32x4*)&dst[(size_t)row * NPOS + pos0 + c16 * 8] = v;
        }
      }
      __syncthreads();                     // tb free for next mode
    }

    // ---- mode g: g = sigmoid(z @ wgate), f32 [pos][cz] direct ----
    {
      f32x4 acc[2][8] = {};
      #pragma unroll
      for (int kk = 0; kk < 4; ++kk) {
        bf16x8 zf[8];
        #pragma unroll
        for (int j = 0; j < 8; ++j) {
          int row = j * 16 + l15, kq = kk * 4 + qd;
          zf[j] = ((const bf16x8*)zl)[(row << 4) | (kq ^ (row & 7))];
        }
        #pragma unroll
        for (int j = 0; j < 8; ++j)
          #pragma unroll
          for (int i = 0; i < 2; ++i)
            acc[i][j] = __builtin_amdgcn_mfma_f32_16x16x32_bf16(wf[4][i][kk], zf[j], acc[i][j], 0, 0, 0);
      }
      #pragma unroll
      for (int i = 0; i < 2; ++i) {
        int cz = w * 32 + i * 16 + qd * 4;
        #pragma unroll
        for (int j = 0; j < 8; ++j) {
          int pos = pos0 + j * 16 + l15;
          float4 pk;
          pk.x = sigm(acc[i][j][0]); pk.y = sigm(acc[i][j][1]);
          pk.z = sigm(acc[i][j][2]); pk.w = sigm(acc[i][j][3]);
          *(float4*)&g[(size_t)pos * CD + cz] = pk;
        }
      }
    }
  }
}

// ---------------- triangle einsum: per channel c, U_c = A_c · B_c^T (bf16) ----------------
__global__ void k_tri(const ushort_t* __restrict__ aT, const ushort_t* __restrict__ bT,
                      ushort_t* __restrict__ uT) {
  __shared__ ushort_t lA[128][32];  // 8KB
  __shared__ ushort_t lB[128][32];
  __shared__ ushort_t tb[128][136]; // 34KB transpose buffer for full-line stores
  const int tid = threadIdx.x;
  const int lane = tid & 63, wid = tid >> 6;
  const int qd = lane >> 4, l15 = lane & 15;
  const int wm = wid & 1, wn = wid >> 1;
  const int c  = blockIdx.z;
  const int m0 = blockIdx.y * 128, n0 = blockIdx.x * 128;
  const ushort_t* A = aT + (size_t)c * NPOS;  // [512][512]
  const ushort_t* B = bT + (size_t)c * NPOS;
  const int sr = tid >> 2, sc = (tid & 3) * 8;   // staging row 0..63, col (ushorts)
  f32x4 acc[4][4] = {};
  for (int kk = 0; kk < N_; kk += 32) {
    __syncthreads();
    *(u32x4*)&lA[sr     ][sc] = *(const u32x4*)&A[(size_t)(m0 + sr)      * N_ + kk + sc];
    *(u32x4*)&lA[sr + 64][sc] = *(const u32x4*)&A[(size_t)(m0 + 64 + sr) * N_ + kk + sc];
    *(u32x4*)&lB[sr     ][sc] = *(const u32x4*)&B[(size_t)(n0 + sr)      * N_ + kk + sc];
    *(u32x4*)&lB[sr + 64][sc] = *(const u32x4*)&B[(size_t)(n0 + 64 + sr) * N_ + kk + sc];
    __syncthreads();
    bf16x8 af[4], bfr[4];
    #pragma unroll
    for (int t = 0; t < 4; ++t) af[t]  = *(const bf16x8*)&lA[wm * 64 + t * 16 + l15][qd * 8];
    #pragma unroll
    for (int t = 0; t < 4; ++t) bfr[t] = *(const bf16x8*)&lB[wn * 64 + t * 16 + l15][qd * 8];
    #pragma unroll
    for (int i = 0; i < 4; ++i)
      #pragma unroll
      for (int j = 0; j < 4; ++j)
        acc[i][j] = __builtin_amdgcn_mfma_f32_16x16x32_bf16(af[i], bfr[j], acc[i][j], 0, 0, 0);
  }
  // epilogue: acc -> tb -> full-line stores (rows of 256B)
  #pragma unroll
  for (int i = 0; i < 4; ++i)
    #pragma unroll
    for (int j = 0; j < 4; ++j)
      #pragma unroll
      for (int r2 = 0; r2 < 4; ++r2)
        tb[wm * 64 + i * 16 + qd * 4 + r2][wn * 64 + j * 16 + l15] = f2bf(acc[i][j][r2]);
  __syncthreads();
  ushort_t* U = uT + (size_t)c * NPOS;
  #pragma unroll
  for (int it = 0; it < 8; ++it) {
    int idx = tid + it * 256;
    int row = idx >> 4, c16 = idx & 15;
    u32x4 v = *(const u32x4*)&tb[row][c16 * 8];
    *(u32x4*)&U[(size_t)(m0 + row) * N_ + n0 + c16 * 8] = v;
  }
}

// ---------------- LN2 + @w_out + gate (f32 gate in d_out, overwritten in place) ----------------
__global__ void k_out(const ushort_t* __restrict__ uT, const ushort_t* __restrict__ wT,
                      const float* __restrict__ g2, const float* __restrict__ b2,
                      float* __restrict__ gout) {
  __shared__ ushort_t nu[128][136];   // [pos][c] padded, 34.8KB (raw then normalized)
  __shared__ float ps[2][128], pq[2][128];
  __shared__ float mu[128], rsd[128], gam[128], bet[128];
  const int tid = threadIdx.x;
  const int lane = tid & 63, wid = tid >> 6;
  const int qd = lane >> 4, l15 = lane & 15;
  const int pos0 = blockIdx.x * 128;
  const ushort_t* WoT = wT + 5 * CD * CD;   // w_outT [cz][c]

  if (tid < 128) { gam[tid] = g2[tid]; bet[tid] = b2[tid]; }

  { // pass 1: load raw U tile (transposed into nu[pos][c]) + LN2 stats
    int p = tid & 127, h = tid >> 7;
    float s = 0.f, sq = 0.f;
    for (int cc = h * 64; cc < h * 64 + 64; ++cc) {
      ushort_t raw = uT[(size_t)cc * NPOS + pos0 + p];
      nu[p][cc] = raw;
      float v = bf2f(raw); s += v; sq += v * v;
    }
    ps[h][p] = s; pq[h][p] = sq;
  }
  __syncthreads();
  if (tid < 128) {
    float s = ps[0][tid] + ps[1][tid];
    float m = s * (1.0f / 128.0f);
    float v = (pq[0][tid] + pq[1][tid]) * (1.0f / 128.0f) - m * m;
    mu[tid] = m; rsd[tid] = rsqrtf(v + 1e-5f);
  }
  __syncthreads();
  { // pass 2: normalize in place
    int p = tid & 127, h = tid >> 7;
    float m = mu[p], rs = rsd[p];
    for (int cc = h * 64; cc < h * 64 + 64; ++cc)
      nu[p][cc] = f2bf((bf2f(nu[p][cc]) - m) * rs * gam[cc] + bet[cc]);
  }
  __syncthreads();

  // GEMM: D[cz][pos] = WoT[cz][c] · nu[pos][c]^T
  const int wm = wid & 1, wn = wid >> 1;
  f32x4 acc[4][4] = {};
  for (int kk = 0; kk < 4; ++kk) {
    bf16x8 af[4];
    #pragma unroll
    for (int i = 0; i < 4; ++i)
      af[i] = *(const bf16x8*)(WoT + (wm * 64 + i * 16 + l15) * CD + kk * 32 + qd * 8);
    #pragma unroll
    for (int j = 0; j < 4; ++j) {
      bf16x8 bn = *(const bf16x8*)&nu[wn * 64 + j * 16 + l15][kk * 32 + qd * 8];
      #pragma unroll
      for (int i = 0; i < 4; ++i)
        acc[i][j] = __builtin_amdgcn_mfma_f32_16x16x32_bf16(af[i], bn, acc[i][j], 0, 0, 0);
    }
  }
  #pragma unroll
  for (int i = 0; i < 4; ++i) {
    int cz = wm * 64 + i * 16 + qd * 4;
    #pragma unroll
    for (int j = 0; j < 4; ++j) {
      int pos = pos0 + wn * 64 + j * 16 + l15;
      float4 gv = *(const float4*)&gout[(size_t)pos * CD + cz];   // read gate first
      float4 pk;
      pk.x = gv.x * acc[i][j][0]; pk.y = gv.y * acc[i][j][1];
      pk.z = gv.z * acc[i][j][2]; pk.w = gv.w * acc[i][j][3];
      *(float4*)&gout[(size_t)pos * CD + cz] = pk;                // overwrite with output
    }
  }
}

extern "C" void kernel_launch(void* const* d_in, const int* in_sizes, int n_in,
                              void* d_out, int out_size, void* d_ws, size_t ws_size,
                              hipStream_t stream) {
  const float* pair = (const float*)d_in[0];
  const float* g1   = (const float*)d_in[1];
  const float* b1   = (const float*)d_in[2];
  const float* wga  = (const float*)d_in[3];
  const float* wgb  = (const float*)d_in[4];
  const float* wa   = (const float*)d_in[5];
  const float* wb   = (const float*)d_in[6];
  const float* g2   = (const float*)d_in[7];
  const float* b2   = (const float*)d_in[8];
  const float* wout = (const float*)d_in[9];
  const float* wg   = (const float*)d_in[10];

  char* ws = (char*)d_ws;
  ushort_t* z  = (ushort_t*)(ws);                 // 64MiB bf16; reused as uT after k_proj
  ushort_t* aT = (ushort_t*)(ws + 67108864);      // 64MiB bf16 [c][pos]
  ushort_t* bT = (ushort_t*)(ws + 134217728);     // 64MiB bf16 [c][pos]
  ushort_t* wT = (ushort_t*)(ws + 201326592);     // 6 * 32KB transposed bf16 weights
  ushort_t* uT = z;
  float*    gb = (float*)d_out;                   // f32 gate staged in d_out, then final output

  k_tw  <<<6, 256, 0, stream>>>(wga, wa, wgb, wb, wg, wout, wT);
  k_ln1 <<<NPOS / 4, 256, 0, stream>>>(pair, g1, b1, z);
  k_proj<<<256, 256, 0, stream>>>(z, wT, aT, bT, gb);
  k_tri <<<dim3(4, 4, 128), 256, 0, stream>>>(aT, bT, uT);
  k_out <<<2048, 256, 0, stream>>>(uT, wT, g2, b2, gb);
}